// Round 4
// baseline (147.893 us; speedup 1.0000x reference)
//
#include <hip/hip_runtime.h>

// Kalman filter scan: B=128, T=256, V=256. One thread per (b,v) track.
// Decoupled-axes algebra (R2): one shared 2x2 Riccati recursion (p00,p01,p11),
// scalar innovation variance, both axes share K. ~20 VALU instr/step.
//
// R3 lesson: compiler DID NOT materialize the ping-pong prefetch (VGPR=72 with
// 192 declared buffer floats) -- it re-sank loads to their uses, exposing full
// memory latency per step at 0.5 waves/SIMD. This round:
//   * one global_load_dwordx4 per step (label,z0,z1,pad) instead of 3 dwords
//   * __builtin_amdgcn_sched_barrier(0) pins each load group ahead of compute
//   * KF_G=16 ping-pong: <=32 outstanding VMEM, ~128 buffer VGPRs (fine at
//     1 wave/SIMD; launch_bounds(64,1))

#define KF_B 128
#define KF_T 256
#define KF_V 256
#define KF_G 16   // steps per prefetch group (ping-pong)

typedef float f4 __attribute__((ext_vector_type(4)));

__device__ inline f4 ld4(const float* p) {
    f4 r;
    __builtin_memcpy(&r, p, sizeof(r));   // <4 x float> align 4 -> global_load_dwordx4
    return r;
}

__global__ __launch_bounds__(64, 1) void kf_kernel(const float* __restrict__ batch,
                                                   float* __restrict__ out) {
    const int tid = blockIdx.x * 64 + threadIdx.x;   // 0 .. B*V-1
    const int b = tid >> 8;          // / V
    const int v = tid & (KF_V - 1);  // % V

    const float* __restrict__ ptr = batch + ((size_t)b * KF_T * KF_V + v) * 3;
    const int stride = KF_V * 3;     // floats between consecutive t

    // shared 2x2 covariance (both axes identical), per-axis states
    float p00 = 1000.f, p01 = 0.f, p11 = 1000.f;
    float x0 = 0.f, v0 = 0.f;
    float x1 = 0.f, v1 = 0.f;

    f4 bufA[KF_G], bufB[KF_G];

    // normal group load: one dwordx4 per step
#define KF_LOAD(dst)                                   \
    do {                                               \
        _Pragma("unroll")                              \
        for (int k = 0; k < KF_G; ++k)                 \
            (dst)[k] = ld4(ptr + k * stride);          \
        ptr += KF_G * stride;                          \
        __builtin_amdgcn_sched_barrier(0);             \
    } while (0)

    // last group: final step loads 3 scalars (no 4B over-read past buffer end)
#define KF_LOAD_LAST(dst)                              \
    do {                                               \
        _Pragma("unroll")                              \
        for (int k = 0; k < KF_G - 1; ++k)             \
            (dst)[k] = ld4(ptr + k * stride);          \
        {                                              \
            const float* q = ptr + (KF_G - 1) * stride;\
            (dst)[KF_G - 1][0] = q[0];                 \
            (dst)[KF_G - 1][1] = q[1];                 \
            (dst)[KF_G - 1][2] = q[2];                 \
            (dst)[KF_G - 1][3] = 0.f;                  \
        }                                              \
        ptr += KF_G * stride;                          \
        __builtin_amdgcn_sched_barrier(0);             \
    } while (0)

#define KF_STEP(o)                                                      \
    do {                                                                \
        const float label = (o)[0];                                     \
        const float z0 = (o)[1];                                        \
        const float z1 = (o)[2];                                        \
        /* predict */                                                   \
        const float xp0 = x0 + v0;                                      \
        const float xp1 = x1 + v1;                                      \
        const float q00 = p00 + 2.f * p01 + p11 + 0.01f;                \
        const float q01 = p01 + p11;                                    \
        const float q11 = p11 + 0.01f;                                  \
        /* scalar innovation variance + masked inverse */               \
        const float S = q00 + 1.f;                                      \
        const float m = (label != -1.0f) ? 1.0f : 0.0f;                 \
        const float is = m * __builtin_amdgcn_rcpf(S);                  \
        const float K0 = q00 * is;                                      \
        const float K1 = q01 * is;                                      \
        /* state update, both axes share K */                           \
        const float y0 = z0 - xp0;                                      \
        const float y1 = z1 - xp1;                                      \
        x0 = xp0 + K0 * y0;                                             \
        v0 = v0 + K1 * y0;                                              \
        x1 = xp1 + K0 * y1;                                             \
        v1 = v1 + K1 * y1;                                              \
        /* covariance update */                                         \
        p00 = q00 - K0 * q00;                                           \
        p01 = q01 - K0 * q01;                                           \
        p11 = q11 - K1 * q01;                                           \
    } while (0)

    // prologue: group 0
    KF_LOAD(bufA);

    const int NG = KF_T / KF_G;   // 16 groups
    for (int g = 0; g < NG; g += 2) {
        if (g + 1 == NG - 1) {
            KF_LOAD_LAST(bufB);
        } else {
            KF_LOAD(bufB);
        }
#pragma unroll
        for (int k = 0; k < KF_G; ++k) KF_STEP(bufA[k]);
        if (g + 2 < NG) {
            if (g + 2 == NG - 1) {
                KF_LOAD_LAST(bufA);
            } else {
                KF_LOAD(bufA);
            }
        }
#pragma unroll
        for (int k = 0; k < KF_G; ++k) KF_STEP(bufB[k]);
    }

    // ---- output: (1, x, y) per track ----
    float* o = out + (size_t)tid * 3;
    o[0] = 1.0f;
    o[1] = x0;
    o[2] = x1;
}

extern "C" void kernel_launch(void* const* d_in, const int* in_sizes, int n_in,
                              void* d_out, int out_size, void* d_ws, size_t ws_size,
                              hipStream_t stream) {
    (void)in_sizes; (void)n_in; (void)d_ws; (void)ws_size; (void)out_size;
    const float* batch = (const float*)d_in[0];
    float* out = (float*)d_out;
    const int total = KF_B * KF_V;            // 32768 threads
    kf_kernel<<<total / 64, 64, 0, stream>>>(batch, out);
}

// Round 8
// 144.923 us; speedup vs baseline: 1.0205x; 1.0205x over previous
//
#include <hip/hip_runtime.h>
#include <stdint.h>

// Kalman filter scan: B=128, T=256, V=256. One thread per (b,v) track.
// Decoupled-axes algebra (R2): one shared 2x2 Riccati recursion (p00,p01,p11),
// scalar innovation variance, both axes share gain K. ~20 VALU instr/step.
//
// R6/R7 lesson: loop-carried asm-load buffers create PHIs; the allocator may
// insert v_mov copies on the backedge. Copying the destination of an IN-FLIGHT
// global_load reads junk (the load lands in the original reg later) -> NaN.
// This round eliminates the mechanism:
//   * load buffers are SCOPED INSIDE the loop body (no PHIs possible)
//   * each body self-drains: issue 16 loads, consume at vmcnt(12/8/4/0);
//     queue is EMPTY at every backedge, so any seam copies read landed data
//   * __launch_bounds__(64,1): lifts the default 8-wave VGPR budget that made
//     the scheduler sink prefetches in R2-R4; ~90 live VGPRs, no pressure

#define KF_B 128
#define KF_T 256
#define KF_V 256

typedef float f4 __attribute__((ext_vector_type(4)));

// one dwordx4: dst <- mem[sbase + voff + imm]
#define GLOAD(dst, sbase, imm)                                         \
    asm volatile("global_load_dwordx4 %0, %1, %2 offset:" #imm         \
                 : "=v"(dst) : "v"(voff), "s"(sbase) : "memory")

// wait until at most N VMEM outstanding; tie regs so uses depend on it
#define WAITVM(N, B)                                                   \
    asm volatile("s_waitcnt vmcnt(" #N ")"                             \
                 : "+v"((B)[0]), "+v"((B)[1]),                         \
                   "+v"((B)[2]), "+v"((B)[3]) :: "memory")

// issue one group's 4 loads (k=0..2 normal; k=3 shifted -4B so the dwordx4
// never reads past the end of the input buffer; t>=3 so never before start)
#define KF_ISSUE(buf)                          \
    do {                                       \
        GLOAD((buf)[0], sb0, 0);               \
        GLOAD((buf)[1], sb0, 3072);            \
        GLOAD((buf)[2], sb1, 0);               \
        GLOAD((buf)[3], sb1, 3068);            \
        sb0 += 12288; sb1 += 12288;            \
    } while (0)

#define KF_STEP3(label, z0, z1)                                         \
    do {                                                                \
        /* predict */                                                   \
        const float xp0 = x0 + v0;                                      \
        const float xp1 = x1 + v1;                                      \
        const float q00 = p00 + 2.f * p01 + p11 + 0.01f;                \
        const float q01 = p01 + p11;                                    \
        const float q11 = p11 + 0.01f;                                  \
        /* scalar innovation variance + masked inverse */               \
        const float S = q00 + 1.f;                                      \
        const float m = ((label) != -1.0f) ? 1.0f : 0.0f;               \
        const float is = m * __builtin_amdgcn_rcpf(S);                  \
        const float K0 = q00 * is;                                      \
        const float K1 = q01 * is;                                      \
        /* state update, both axes share K */                           \
        const float y0 = (z0) - xp0;                                    \
        const float y1 = (z1) - xp1;                                    \
        x0 = xp0 + K0 * y0;                                             \
        v0 = v0 + K1 * y0;                                              \
        x1 = xp1 + K0 * y1;                                             \
        v1 = v1 + K1 * y1;                                              \
        /* covariance update */                                         \
        p00 = q00 - K0 * q00;                                           \
        p01 = q01 - K0 * q01;                                           \
        p11 = q11 - K1 * q01;                                           \
    } while (0)

// consume 4 steps; k=3 came from the shifted load -> components [1],[2],[3]
#define KF_CONSUME(B)                                        \
    do {                                                     \
        KF_STEP3((B)[0][0], (B)[0][1], (B)[0][2]);           \
        KF_STEP3((B)[1][0], (B)[1][1], (B)[1][2]);           \
        KF_STEP3((B)[2][0], (B)[2][1], (B)[2][2]);           \
        KF_STEP3((B)[3][1], (B)[3][2], (B)[3][3]);           \
    } while (0)

__global__ __launch_bounds__(64, 1) void kf_kernel(const float* __restrict__ batch,
                                                   float* __restrict__ out) {
    // b uniform from blockIdx only (provably scalar); v per-lane.
    const int blk = blockIdx.x;
    const int b = blk >> 2;                              // 0..127, SGPR
    const int v = ((blk & 3) << 6) | threadIdx.x;        // 0..255, VGPR

    // SADDR+voffset addressing: uniform scalar bases, per-lane byte offset
    const uint32_t voff = (uint32_t)v * 12u;
    uint64_t sb0 = (uint64_t)batch + (uint64_t)b * (KF_T * KF_V * 3 * 4);
    uint64_t sb1 = sb0 + 6144;   // covers k=2 (off 0) and k=3 (off 3068)

    // shared 2x2 covariance (both axes identical), per-axis states
    float p00 = 1000.f, p01 = 0.f, p11 = 1000.f;
    float x0 = 0.f, v0 = 0.f;
    float x1 = 0.f, v1 = 0.f;

    // 16 bodies x 16 steps. Buffers are body-local (no PHIs); each body
    // issues its 16 loads up front and drains to vmcnt(0) before the seam.
#pragma unroll 1
    for (int body = 0; body < 16; ++body) {
        f4 g0[4], g1[4], g2[4], g3[4];
        KF_ISSUE(g0);
        KF_ISSUE(g1);
        KF_ISSUE(g2);
        KF_ISSUE(g3);
        WAITVM(12, g0); KF_CONSUME(g0);
        WAITVM(8,  g1); KF_CONSUME(g1);
        WAITVM(4,  g2); KF_CONSUME(g2);
        WAITVM(0,  g3); KF_CONSUME(g3);
    }

    // ---- output: (1, x, y) per track ----
    const int tid = blk * 64 + threadIdx.x;
    float* o = out + (size_t)tid * 3;
    o[0] = 1.0f;
    o[1] = x0;
    o[2] = x1;
}

extern "C" void kernel_launch(void* const* d_in, const int* in_sizes, int n_in,
                              void* d_out, int out_size, void* d_ws, size_t ws_size,
                              hipStream_t stream) {
    (void)in_sizes; (void)n_in; (void)d_ws; (void)ws_size; (void)out_size;
    const float* batch = (const float*)d_in[0];
    float* out = (float*)d_out;
    const int total = KF_B * KF_V;            // 32768 threads, 512 waves
    kf_kernel<<<total / 64, 64, 0, stream>>>(batch, out);
}